// Round 2
// baseline (308.416 us; speedup 1.0000x reference)
//
#include <hip/hip_runtime.h>
#include <math.h>

#define BB 16
#define TT 2048
#define CC 1024
#define HH 64
#define MTOT (BB*TT)

typedef _Float16 f16;
typedef _Float16 f16x8 __attribute__((ext_vector_type(8)));
typedef float f32x4 __attribute__((ext_vector_type(4)));

// ws layout (f16 element offsets):
//   Wt [192][1024]   n-major transposed weights (q|k|v)
//   q  [32768][64]   row-major, pre-scaled by log2(e)/8
//   k  [32768][64]   row-major
//   vT [64][32768]   h-major transposed v
#define WT_OFF 0
#define Q_OFF  196608
#define K_OFF  (Q_OFF + (size_t)MTOT*HH)
#define VT_OFF (K_OFF + (size_t)MTOT*HH)

__device__ __forceinline__ void async16(const void* g, void* l) {
    __builtin_amdgcn_global_load_lds(
        (const __attribute__((address_space(1))) unsigned int*)g,
        (__attribute__((address_space(3))) unsigned int*)l, 16, 0, 0);
}

__device__ __forceinline__ f16x8 cvt8(float4 u, float4 v) {
    f16x8 r;
    r[0] = (f16)u.x; r[1] = (f16)u.y; r[2] = (f16)u.z; r[3] = (f16)u.w;
    r[4] = (f16)v.x; r[5] = (f16)v.y; r[6] = (f16)v.z; r[7] = (f16)v.w;
    return r;
}

// ---------------- Kernel 0: W transpose + convert (coalesced via LDS) ----------------
__global__ __launch_bounds__(256) void prep_kernel(
    const float* __restrict__ Wq, const float* __restrict__ Wk,
    const float* __restrict__ Wv, f16* __restrict__ ws)
{
    __shared__ f16 Ls[64][72];
    const int which = blockIdx.x >> 4, k0 = (blockIdx.x & 15) * 64;
    const float* W = (which == 0) ? Wq : (which == 1) ? Wk : Wv;
    const int t = threadIdx.x;
    const int kr = t >> 2, cb = t & 3;
    #pragma unroll
    for (int i = 0; i < 4; ++i) {
        float4 v = *(const float4*)(W + (size_t)(k0 + kr) * HH + cb * 16 + i * 4);
        Ls[kr][cb * 16 + i * 4 + 0] = (f16)v.x;
        Ls[kr][cb * 16 + i * 4 + 1] = (f16)v.y;
        Ls[kr][cb * 16 + i * 4 + 2] = (f16)v.z;
        Ls[kr][cb * 16 + i * 4 + 3] = (f16)v.w;
    }
    __syncthreads();
    const int n = t >> 2, kc = (t & 3) * 16;
    f16x8 o0, o1;
    #pragma unroll
    for (int i = 0; i < 8; ++i) o0[i] = Ls[kc + i][n];
    #pragma unroll
    for (int i = 0; i < 8; ++i) o1[i] = Ls[kc + 8 + i][n];
    f16* dst = ws + WT_OFF + (size_t)(which * 64 + n) * CC + k0 + kc;
    *(f16x8*)dst = o0;
    *(f16x8*)(dst + 8) = o1;
}

// ---------------- Kernel 1: QKV projection (barrier-free, direct-global) ----------------
// v3: NO LDS staging in the K-loop, NO barriers. A-frags (X, fp32->f16 cvt in
// regs) and B-frags (Wt, f16) are contiguous 16B in exactly MFMA layout:
//   A: lane(c,g) reads X[m0+mt*16+c][k0+kk*32+8g .. +7]  (two float4)
//   B: lane(c,g) reads Wt[(3w+j)*16+c][k0+kk*32+8g .. +7] (one f16x8)
// X rows identical across the 4 waves -> L1-served; Wt (384KB) L2-resident.
// BM=32 -> 1024 blocks -> 4 blocks/CU dispatched, 3 resident (launch_bounds
// (256,3) caps VGPR at ~170 so X and W are both register-double-buffered).
// Waves slip freely: latency hidden by TLP, not by a lockstep pipeline.
__global__ __launch_bounds__(256, 3) void qkv_kernel(
    const float* __restrict__ x,
    const float* __restrict__ bq, const float* __restrict__ bk,
    const float* __restrict__ bv, f16* __restrict__ ws)
{
    __shared__ __align__(16) f16 Vt[64][36];   // 4.5 KB epilogue transpose only

    const f16* wt = ws + WT_OFF;
    const int tid  = threadIdx.x;
    const int lane = tid & 63, w = tid >> 6;
    const int c = lane & 15, g = lane >> 4;
    const int m0 = blockIdx.x * 32;

    f32x4 acc[2][3];
    #pragma unroll
    for (int mt = 0; mt < 2; ++mt)
        #pragma unroll
        for (int j = 0; j < 3; ++j) acc[mt][j] = (f32x4){0.f, 0.f, 0.f, 0.f};

    float4 xv[2][8];   // [buf][mt*4 + kk*2 + half]
    f16x8  wv[2][6];   // [buf][j*2 + kk]

    const float* xr0 = x + (size_t)(m0 + c) * CC + 8 * g;        // mt=0 row
    const float* xr1 = x + (size_t)(m0 + 16 + c) * CC + 8 * g;   // mt=1 row
    const f16* wr[3];
    #pragma unroll
    for (int j = 0; j < 3; ++j)
        wr[j] = wt + (size_t)((3 * w + j) * 16 + c) * CC + 8 * g;

    #define LOADSTEP(buf, k0)                                             \
        do {                                                              \
            _Pragma("unroll")                                             \
            for (int kk = 0; kk < 2; ++kk) {                              \
                xv[buf][0 * 4 + kk * 2 + 0] = *(const float4*)(xr0 + (k0) + kk * 32);     \
                xv[buf][0 * 4 + kk * 2 + 1] = *(const float4*)(xr0 + (k0) + kk * 32 + 4); \
                xv[buf][1 * 4 + kk * 2 + 0] = *(const float4*)(xr1 + (k0) + kk * 32);     \
                xv[buf][1 * 4 + kk * 2 + 1] = *(const float4*)(xr1 + (k0) + kk * 32 + 4); \
            }                                                             \
            _Pragma("unroll")                                             \
            for (int j = 0; j < 3; ++j)                                   \
                _Pragma("unroll")                                         \
                for (int kk = 0; kk < 2; ++kk)                            \
                    wv[buf][j * 2 + kk] = *(const f16x8*)(wr[j] + (k0) + kk * 32); \
        } while (0)

    #define COMPSTEP(buf)                                                 \
        do {                                                              \
            _Pragma("unroll")                                             \
            for (int kk = 0; kk < 2; ++kk) {                              \
                f16x8 a0 = cvt8(xv[buf][kk * 2], xv[buf][kk * 2 + 1]);    \
                f16x8 a1 = cvt8(xv[buf][4 + kk * 2], xv[buf][4 + kk * 2 + 1]); \
                _Pragma("unroll")                                         \
                for (int j = 0; j < 3; ++j) {                             \
                    acc[0][j] = __builtin_amdgcn_mfma_f32_16x16x32_f16(   \
                        a0, wv[buf][j * 2 + kk], acc[0][j], 0, 0, 0);     \
                    acc[1][j] = __builtin_amdgcn_mfma_f32_16x16x32_f16(   \
                        a1, wv[buf][j * 2 + kk], acc[1][j], 0, 0, 0);     \
                }                                                         \
            }                                                             \
        } while (0)

    LOADSTEP(0, 0);
    #pragma unroll
    for (int t = 0; t < 16; ++t) {
        if (t < 15) LOADSTEP((t + 1) & 1, (t + 1) * 64);
        COMPSTEP(t & 1);
    }
    #undef LOADSTEP
    #undef COMPSTEP

    // epilogue: C/D row = 4g+r (in 16-tile), col = nt*16+c
    const float QSCALE = 0.125f * 1.44269504089f;   // fold log2(e) for exp2 softmax
    #pragma unroll
    for (int j = 0; j < 3; ++j) {
        int nt = 3 * w + j;
        int plane = nt >> 2;             // 0=q 1=k 2=v
        int h = (nt & 3) * 16 + c;
        if (plane == 0) {
            float bias = bq[h];
            #pragma unroll
            for (int mt = 0; mt < 2; ++mt)
                #pragma unroll
                for (int r = 0; r < 4; ++r) {
                    int m = m0 + mt * 16 + 4 * g + r;
                    ws[Q_OFF + (size_t)m * HH + h] =
                        (f16)((acc[mt][j][r] + bias) * QSCALE);
                }
        } else if (plane == 1) {
            float bias = bk[h];
            #pragma unroll
            for (int mt = 0; mt < 2; ++mt)
                #pragma unroll
                for (int r = 0; r < 4; ++r) {
                    int m = m0 + mt * 16 + 4 * g + r;
                    ws[K_OFF + (size_t)m * HH + h] = (f16)(acc[mt][j][r] + bias);
                }
        } else {
            float bias = bv[h];
            #pragma unroll
            for (int mt = 0; mt < 2; ++mt)
                #pragma unroll
                for (int r = 0; r < 4; ++r)
                    Vt[h][mt * 16 + 4 * g + r] = (f16)(acc[mt][j][r] + bias);
        }
    }
    __syncthreads();
    if (tid < 128) {   // coalesced vT write: thread t -> row h=t>>1, 16-col seg t&1
        int h = tid >> 1, seg = tid & 1;
        f16* dst = ws + VT_OFF + (size_t)h * MTOT + m0 + seg * 16;
        *(f16x8*)dst       = *(f16x8*)&Vt[h][seg * 16];
        *(f16x8*)(dst + 8) = *(f16x8*)&Vt[h][seg * 16 + 8];
    }
}

// ---------------- Kernel 2: causal flash attention ----------------
// v3 = round-0 (known-good) sync structure, with two safe deltas:
//  - Q fragments read DIRECT from global (wave-private, loop-invariant):
//    kills the Qs LDS buffer and the per-tile aq re-reads.
//  - exp -> exp2 (log2(e) pre-folded into Q by qkv): saves 16 v_mul/lane/tile.
__global__ __launch_bounds__(256, 2) void attn_kernel(
    const f16* __restrict__ ws, float* __restrict__ out)
{
    const f16* qp = ws + Q_OFF;
    const f16* kp = ws + K_OFF;
    const f16* vt = ws + VT_OFF;

    __shared__ __align__(16) f16 Ks[64 * 64];
    __shared__ __align__(16) f16 Vs[64 * 64];
    __shared__ __align__(16) f16 Ps[4][16][72];   // wave-private P round-trip

    const int tid  = threadIdx.x;
    const int lane = tid & 63, w = tid >> 6;
    const int c = lane & 15, g = lane >> 4;

    // swizzle: XCD r8 gets batches 2r8,2r8+1; blocks i,i+256 complementary
    const int id = blockIdx.x;
    const int r8 = id & 7, j = id >> 3;
    const int half = j >> 5, qr = j & 31;
    const int b  = 2 * r8 + half;
    const int qi = half ? (31 - qr) : qr;
    const int q0 = qi * 64;
    const size_t rowbase = (size_t)b * TT;

    // direct-global, loop-invariant Q A-fragments (wave-private rows)
    const f16* qrow = qp + (rowbase + q0 + w * 16 + c) * HH;
    const f16x8 aq0 = *(const f16x8*)(qrow + 8 * g);
    const f16x8 aq1 = *(const f16x8*)(qrow + 32 + 8 * g);

    f32x4 o[5];   // 4 output n-tiles + ones-column (row-sum l)
    #pragma unroll
    for (int nt = 0; nt < 5; ++nt) o[nt] = (f32x4){0.f, 0.f, 0.f, 0.f};

    f16x8 onesf;
    #pragma unroll
    for (int i = 0; i < 8; ++i) onesf[i] = (c == 0) ? (f16)1.0f : (f16)0.0f;

    for (int st = 0; st <= qi; ++st) {
        const int s0 = st * 64;
        __syncthreads();   // prev tile's fragment reads done
        #pragma unroll
        for (int i = 0; i < 2; ++i) {
            int G0 = (w * 2 + i) * 64;
            int G = G0 + lane;
            int r = G >> 3, q = G & 7;
            int sw = (q ^ (r & 7)) << 3;
            async16(kp + (rowbase + s0 + r) * HH + sw, Ks + G0 * 8);
            async16(vt + (size_t)r * MTOT + rowbase + s0 + sw, Vs + G0 * 8);
        }
        __syncthreads();   // staged data visible

        // S = Q K^T : 8 mfma
        f32x4 s[4];
        #pragma unroll
        for (int nt = 0; nt < 4; ++nt) {
            s[nt] = (f32x4){0.f, 0.f, 0.f, 0.f};
            int r = nt * 16 + c;
            f16x8 b0 = *(const f16x8*)(Ks + r * 64 + ((g       ^ (c & 7)) << 3));
            f16x8 b1 = *(const f16x8*)(Ks + r * 64 + (((4 + g) ^ (c & 7)) << 3));
            s[nt] = __builtin_amdgcn_mfma_f32_16x16x32_f16(aq0, b0, s[nt], 0, 0, 0);
            s[nt] = __builtin_amdgcn_mfma_f32_16x16x32_f16(aq1, b1, s[nt], 0, 0, 0);
        }

        if (st == qi) {   // diagonal tile: causal mask
            #pragma unroll
            for (int nt = 0; nt < 4; ++nt)
                #pragma unroll
                for (int rr = 0; rr < 4; ++rr)
                    if (nt * 16 + c > w * 16 + 4 * g + rr) s[nt][rr] = -INFINITY;
        }

        // P = exp2(S) (Q pre-scaled by log2e; scores bounded, no running max)
        #pragma unroll
        for (int nt = 0; nt < 4; ++nt)
            #pragma unroll
            for (int rr = 0; rr < 4; ++rr)
                Ps[w][4 * g + rr][nt * 16 + c] = (f16)__builtin_exp2f(s[nt][rr]);
        // in-wave RAW on Ps: compiler orders via lgkmcnt, no barrier needed
        f16x8 pa0 = *(f16x8*)&Ps[w][c][g * 8];
        f16x8 pa1 = *(f16x8*)&Ps[w][c][32 + g * 8];

        // O += P V (+ ones column for l): 10 mfma
        #pragma unroll
        for (int nt = 0; nt < 4; ++nt) {
            int r = nt * 16 + c;
            f16x8 v0 = *(const f16x8*)(Vs + r * 64 + ((g       ^ (c & 7)) << 3));
            f16x8 v1 = *(const f16x8*)(Vs + r * 64 + (((4 + g) ^ (c & 7)) << 3));
            o[nt] = __builtin_amdgcn_mfma_f32_16x16x32_f16(pa0, v0, o[nt], 0, 0, 0);
            o[nt] = __builtin_amdgcn_mfma_f32_16x16x32_f16(pa1, v1, o[nt], 0, 0, 0);
        }
        o[4] = __builtin_amdgcn_mfma_f32_16x16x32_f16(pa0, onesf, o[4], 0, 0, 0);
        o[4] = __builtin_amdgcn_mfma_f32_16x16x32_f16(pa1, onesf, o[4], 0, 0, 0);
    }

    // epilogue: l sits at col 0 of each 16-lane group -> broadcast, normalize
    #pragma unroll
    for (int rr = 0; rr < 4; ++rr) {
        float lv = __shfl(o[4][rr], lane & 48);
        float inv = 1.0f / lv;
        int mrow = q0 + w * 16 + 4 * g + rr;
        #pragma unroll
        for (int nt = 0; nt < 4; ++nt)
            out[(rowbase + mrow) * HH + nt * 16 + c] = o[nt][rr] * inv;
    }
}

extern "C" void kernel_launch(void* const* d_in, const int* in_sizes, int n_in,
                              void* d_out, int out_size, void* d_ws, size_t ws_size,
                              hipStream_t stream) {
    const float* x  = (const float*)d_in[0];
    const float* Wq = (const float*)d_in[1];
    const float* bq = (const float*)d_in[2];
    const float* Wk = (const float*)d_in[3];
    const float* bk = (const float*)d_in[4];
    const float* Wv = (const float*)d_in[5];
    const float* bv = (const float*)d_in[6];
    f16*   ws  = (f16*)d_ws;
    float* out = (float*)d_out;

    prep_kernel<<<48, 256, 0, stream>>>(Wq, Wk, Wv, ws);
    qkv_kernel<<<MTOT / 32, 256, 0, stream>>>(x, bq, bk, bv, ws);
    attn_kernel<<<512, 256, 0, stream>>>(ws, out);
}

// Round 3
// 248.303 us; speedup vs baseline: 1.2421x; 1.2421x over previous
//
#include <hip/hip_runtime.h>
#include <math.h>

#define BB 16
#define TT 2048
#define CC 1024
#define HH 64
#define MTOT (BB*TT)

typedef _Float16 f16;
typedef _Float16 f16x8 __attribute__((ext_vector_type(8)));
typedef float f32x4 __attribute__((ext_vector_type(4)));

// ws layout (f16 element offsets):
//   Wt [192][1024]   n-major transposed weights (q|k|v)
//   q  [32768][64]   row-major, pre-scaled by log2(e)/8
//   k  [32768][64]   row-major
//   vT [64][32768]   h-major transposed v
#define WT_OFF 0
#define Q_OFF  196608
#define K_OFF  (Q_OFF + (size_t)MTOT*HH)
#define VT_OFF (K_OFF + (size_t)MTOT*HH)

__device__ __forceinline__ void async16(const void* g, void* l) {
    __builtin_amdgcn_global_load_lds(
        (const __attribute__((address_space(1))) unsigned int*)g,
        (__attribute__((address_space(3))) unsigned int*)l, 16, 0, 0);
}

__device__ __forceinline__ f16x8 cvt8(float4 u, float4 v) {
    f16x8 r;
    r[0] = (f16)u.x; r[1] = (f16)u.y; r[2] = (f16)u.z; r[3] = (f16)u.w;
    r[4] = (f16)v.x; r[5] = (f16)v.y; r[6] = (f16)v.z; r[7] = (f16)v.w;
    return r;
}

// ---------------- Kernel 0: W transpose + convert (coalesced via LDS) ----------------
__global__ __launch_bounds__(256) void prep_kernel(
    const float* __restrict__ Wq, const float* __restrict__ Wk,
    const float* __restrict__ Wv, f16* __restrict__ ws)
{
    __shared__ f16 Ls[64][72];
    const int which = blockIdx.x >> 4, k0 = (blockIdx.x & 15) * 64;
    const float* W = (which == 0) ? Wq : (which == 1) ? Wk : Wv;
    const int t = threadIdx.x;
    const int kr = t >> 2, cb = t & 3;
    #pragma unroll
    for (int i = 0; i < 4; ++i) {
        float4 v = *(const float4*)(W + (size_t)(k0 + kr) * HH + cb * 16 + i * 4);
        Ls[kr][cb * 16 + i * 4 + 0] = (f16)v.x;
        Ls[kr][cb * 16 + i * 4 + 1] = (f16)v.y;
        Ls[kr][cb * 16 + i * 4 + 2] = (f16)v.z;
        Ls[kr][cb * 16 + i * 4 + 3] = (f16)v.w;
    }
    __syncthreads();
    const int n = t >> 2, kc = (t & 3) * 16;
    f16x8 o0, o1;
    #pragma unroll
    for (int i = 0; i < 8; ++i) o0[i] = Ls[kc + i][n];
    #pragma unroll
    for (int i = 0; i < 8; ++i) o1[i] = Ls[kc + 8 + i][n];
    f16* dst = ws + WT_OFF + (size_t)(which * 64 + n) * CC + k0 + kc;
    *(f16x8*)dst = o0;
    *(f16x8*)(dst + 8) = o1;
}

// ---------------- Kernel 1: QKV projection (R0-exact structure) ----------------
// BM=64, N=192, BK=64. 512 blocks x 4 waves, 49KB LDS -> 3 blocks/CU.
// Reverted to the measured-best round-0 code; only change: Q epilogue scale
// carries log2(e) so attention can use exp2.
__global__ __launch_bounds__(256, 2) void qkv_kernel(
    const float* __restrict__ x,
    const float* __restrict__ bq, const float* __restrict__ bk,
    const float* __restrict__ bv, f16* __restrict__ ws)
{
    __shared__ __align__(16) float Xs[64 * 64];   // 16 KB, granule-swizzled
    __shared__ __align__(16) f16   Ws[192 * 64];  // 24 KB, granule-swizzled
    __shared__ __align__(16) f16   Vt[64][72];    //  9 KB epilogue transpose

    const f16* wt = ws + WT_OFF;
    const int tid  = threadIdx.x;
    const int lane = tid & 63, w = tid >> 6;
    const int c = lane & 15, g = lane >> 4;
    const int m0 = blockIdx.x * 64;

    f32x4 acc[4][3];     // [mt][j]
    #pragma unroll
    for (int mt = 0; mt < 4; ++mt)
        #pragma unroll
        for (int j = 0; j < 3; ++j) acc[mt][j] = (f32x4){0.f, 0.f, 0.f, 0.f};

    for (int k0 = 0; k0 < CC; k0 += 64) {
        __syncthreads();   // previous iteration's fragment reads done
        // stage X tile (64x64 fp32): 1024 granules, 4 calls/wave
        #pragma unroll
        for (int i = 0; i < 4; ++i) {
            int G0 = (w * 4 + i) * 64;
            int G = G0 + lane;
            int r = G >> 4, q = G & 15;
            async16(x + (size_t)(m0 + r) * CC + k0 + ((q ^ (r & 15)) << 2),
                    Xs + G0 * 4);
        }
        // stage W tile (192x64 f16): 1536 granules, 6 calls/wave
        #pragma unroll
        for (int i = 0; i < 6; ++i) {
            int G0 = (w * 6 + i) * 64;
            int G = G0 + lane;
            int r = G >> 3, q = G & 7;
            async16(wt + (size_t)r * CC + k0 + ((q ^ (r & 7)) << 3),
                    Ws + G0 * 8);
        }
        __syncthreads();   // vmcnt drain: staged data visible

        #pragma unroll
        for (int kk = 0; kk < 2; ++kk) {
            f16x8 bfr[3];
            #pragma unroll
            for (int j = 0; j < 3; ++j) {
                int r = (3 * w + j) * 16 + c;
                int p = (kk * 4 + g) ^ (c & 7);
                bfr[j] = *(const f16x8*)(Ws + r * 64 + p * 8);
            }
            #pragma unroll
            for (int mt = 0; mt < 4; ++mt) {
                int r = mt * 16 + c;
                int q = kk * 8 + 2 * g;
                float4 f0 = *(const float4*)(Xs + r * 64 + (q ^ c) * 4);
                float4 f1 = *(const float4*)(Xs + r * 64 + ((q + 1) ^ c) * 4);
                f16x8 a = cvt8(f0, f1);
                #pragma unroll
                for (int j = 0; j < 3; ++j)
                    acc[mt][j] = __builtin_amdgcn_mfma_f32_16x16x32_f16(
                        a, bfr[j], acc[mt][j], 0, 0, 0);
            }
        }
    }

    // epilogue: C/D row = 4g+r (in 16-tile), col = nt*16+c
    const float QSCALE = 0.125f * 1.44269504089f;   // fold log2(e) for exp2
    #pragma unroll
    for (int j = 0; j < 3; ++j) {
        int nt = 3 * w + j;
        int plane = nt >> 2;             // 0=q 1=k 2=v
        int h = (nt & 3) * 16 + c;
        if (plane == 0) {
            float bias = bq[h];
            #pragma unroll
            for (int mt = 0; mt < 4; ++mt)
                #pragma unroll
                for (int r = 0; r < 4; ++r) {
                    int m = m0 + mt * 16 + 4 * g + r;
                    ws[Q_OFF + (size_t)m * HH + h] =
                        (f16)((acc[mt][j][r] + bias) * QSCALE);
                }
        } else if (plane == 1) {
            float bias = bk[h];
            #pragma unroll
            for (int mt = 0; mt < 4; ++mt)
                #pragma unroll
                for (int r = 0; r < 4; ++r) {
                    int m = m0 + mt * 16 + 4 * g + r;
                    ws[K_OFF + (size_t)m * HH + h] = (f16)(acc[mt][j][r] + bias);
                }
        } else {
            float bias = bv[h];
            #pragma unroll
            for (int mt = 0; mt < 4; ++mt)
                #pragma unroll
                for (int r = 0; r < 4; ++r)
                    Vt[h][mt * 16 + 4 * g + r] = (f16)(acc[mt][j][r] + bias);
        }
    }
    __syncthreads();
    {   // coalesced vT write: thread t -> row h=t>>2, 16-col segment t&3
        int h = tid >> 2, seg = tid & 3;
        f16* dst = ws + VT_OFF + (size_t)h * MTOT + m0 + seg * 16;
        *(f16x8*)dst       = *(f16x8*)&Vt[h][seg * 16];
        *(f16x8*)(dst + 8) = *(f16x8*)&Vt[h][seg * 16 + 8];
    }
}

// ---------------- Kernel 2: causal flash attention (TLP restructure) ----------------
// v4: same per-tile math/sync as round-0 (measured-good), but 128-thread
// blocks on 32-row q-tiles -> 1024 blocks, 20.5KB LDS, 4 co-resident
// independent blocks/CU (vs 2): per-tile barrier/latency stalls of one block
// are covered by the other blocks' compute. Q read direct from global
// (loop-invariant, wave-private) -> Qs LDS and per-tile aq re-reads gone.
// exp -> exp2 (log2(e) folded into Q by qkv).
__global__ __launch_bounds__(128, 3) void attn_kernel(
    const f16* __restrict__ ws, float* __restrict__ out)
{
    const f16* qp = ws + Q_OFF;
    const f16* kp = ws + K_OFF;
    const f16* vt = ws + VT_OFF;

    __shared__ __align__(16) f16 Ks[64 * 64];     // 8 KB
    __shared__ __align__(16) f16 Vs[64 * 64];     // 8 KB
    __shared__ __align__(16) f16 Ps[2][16][72];   // 4.5 KB wave-private P

    const int tid  = threadIdx.x;
    const int lane = tid & 63, w = tid >> 6;      // w in {0,1}
    const int c = lane & 15, g = lane >> 4;

    // swizzle: XCD r8 gets batches 2r8,2r8+1; ids j and j+64 (same CU slot)
    // get complementary qi -> per-CU tile counts balanced.
    const int id = blockIdx.x;
    const int r8 = id & 7, j = id >> 3;           // j in 0..127
    const int half = j >> 6, qr = j & 63;
    const int b  = 2 * r8 + half;
    const int qi = half ? (63 - qr) : qr;         // 32-row q-tile index 0..63
    const int q0 = qi * 32;
    const int stmax = qi >> 1;                    // KV tiles are 64 rows
    const size_t rowbase = (size_t)b * TT;

    // direct-global, loop-invariant Q A-fragments (wave rows q0+16w .. +15)
    const f16* qrow = qp + (rowbase + q0 + w * 16 + c) * HH;
    const f16x8 aq0 = *(const f16x8*)(qrow + 8 * g);
    const f16x8 aq1 = *(const f16x8*)(qrow + 32 + 8 * g);

    f32x4 o[5];   // 4 output n-tiles + ones-column (row-sum l)
    #pragma unroll
    for (int nt = 0; nt < 5; ++nt) o[nt] = (f32x4){0.f, 0.f, 0.f, 0.f};

    f16x8 onesf;
    #pragma unroll
    for (int i = 0; i < 8; ++i) onesf[i] = (c == 0) ? (f16)1.0f : (f16)0.0f;

    for (int st = 0; st <= stmax; ++st) {
        const int s0 = st * 64;
        __syncthreads();   // prev tile's fragment reads done
        // stage K,V (64x64 f16 each): 512 granules each, 4 calls/wave each
        #pragma unroll
        for (int i = 0; i < 4; ++i) {
            int G0 = (w * 4 + i) * 64;
            int G = G0 + lane;
            int r = G >> 3, q = G & 7;
            int sw = (q ^ (r & 7)) << 3;
            async16(kp + (rowbase + s0 + r) * HH + sw, Ks + G0 * 8);
            async16(vt + (size_t)r * MTOT + rowbase + s0 + sw, Vs + G0 * 8);
        }
        __syncthreads();   // staged data visible

        // S = Q K^T : 8 mfma
        f32x4 s[4];
        #pragma unroll
        for (int nt = 0; nt < 4; ++nt) {
            s[nt] = (f32x4){0.f, 0.f, 0.f, 0.f};
            int r = nt * 16 + c;
            f16x8 b0 = *(const f16x8*)(Ks + r * 64 + ((g       ^ (c & 7)) << 3));
            f16x8 b1 = *(const f16x8*)(Ks + r * 64 + (((4 + g) ^ (c & 7)) << 3));
            s[nt] = __builtin_amdgcn_mfma_f32_16x16x32_f16(aq0, b0, s[nt], 0, 0, 0);
            s[nt] = __builtin_amdgcn_mfma_f32_16x16x32_f16(aq1, b1, s[nt], 0, 0, 0);
        }

        if (st == stmax) {   // diagonal tile: causal mask
            const int doff = q0 - s0;   // 0 (even qi) or 32 (odd qi)
            #pragma unroll
            for (int nt = 0; nt < 4; ++nt)
                #pragma unroll
                for (int rr = 0; rr < 4; ++rr)
                    if (nt * 16 + c > doff + w * 16 + 4 * g + rr)
                        s[nt][rr] = -INFINITY;
        }

        // P = exp2(S) (Q pre-scaled by log2e; scores bounded, no running max)
        #pragma unroll
        for (int nt = 0; nt < 4; ++nt)
            #pragma unroll
            for (int rr = 0; rr < 4; ++rr)
                Ps[w][4 * g + rr][nt * 16 + c] = (f16)__builtin_exp2f(s[nt][rr]);
        // in-wave RAW on Ps: compiler orders via lgkmcnt, no barrier needed
        f16x8 pa0 = *(f16x8*)&Ps[w][c][g * 8];
        f16x8 pa1 = *(f16x8*)&Ps[w][c][32 + g * 8];

        // O += P V (+ ones column for l): 10 mfma
        #pragma unroll
        for (int nt = 0; nt < 4; ++nt) {
            int r = nt * 16 + c;
            f16x8 v0 = *(const f16x8*)(Vs + r * 64 + ((g       ^ (c & 7)) << 3));
            f16x8 v1 = *(const f16x8*)(Vs + r * 64 + (((4 + g) ^ (c & 7)) << 3));
            o[nt] = __builtin_amdgcn_mfma_f32_16x16x32_f16(pa0, v0, o[nt], 0, 0, 0);
            o[nt] = __builtin_amdgcn_mfma_f32_16x16x32_f16(pa1, v1, o[nt], 0, 0, 0);
        }
        o[4] = __builtin_amdgcn_mfma_f32_16x16x32_f16(pa0, onesf, o[4], 0, 0, 0);
        o[4] = __builtin_amdgcn_mfma_f32_16x16x32_f16(pa1, onesf, o[4], 0, 0, 0);
    }

    // epilogue: l sits at col 0 of each 16-lane group -> broadcast, normalize
    #pragma unroll
    for (int rr = 0; rr < 4; ++rr) {
        float lv = __shfl(o[4][rr], lane & 48);
        float inv = 1.0f / lv;
        int mrow = q0 + w * 16 + 4 * g + rr;
        #pragma unroll
        for (int nt = 0; nt < 4; ++nt)
            out[(rowbase + mrow) * HH + nt * 16 + c] = o[nt][rr] * inv;
    }
}

extern "C" void kernel_launch(void* const* d_in, const int* in_sizes, int n_in,
                              void* d_out, int out_size, void* d_ws, size_t ws_size,
                              hipStream_t stream) {
    const float* x  = (const float*)d_in[0];
    const float* Wq = (const float*)d_in[1];
    const float* bq = (const float*)d_in[2];
    const float* Wk = (const float*)d_in[3];
    const float* bk = (const float*)d_in[4];
    const float* Wv = (const float*)d_in[5];
    const float* bv = (const float*)d_in[6];
    f16*   ws  = (f16*)d_ws;
    float* out = (float*)d_out;

    prep_kernel<<<48, 256, 0, stream>>>(Wq, Wk, Wv, ws);
    qkv_kernel<<<MTOT / 64, 256, 0, stream>>>(x, bq, bk, bv, ws);
    attn_kernel<<<1024, 128, 0, stream>>>(ws, out);
}